// Round 11
// baseline (1799.861 us; speedup 1.0000x reference)
//
#include <hip/hip_runtime.h>
#include <math.h>

#define NROWS 16384
#define FC 96
#define T 512
#define NRI 1024
#define LAYERS 16
#define NBLK 256

typedef _Float16 f16;
typedef _Float16 half8 __attribute__((ext_vector_type(8)));
typedef _Float16 half4 __attribute__((ext_vector_type(4)));
typedef float floatx4 __attribute__((ext_vector_type(4)));

// ws float offsets
#define OFF_MAXKEY 0                             // 1 uint (monotone-encoded float max)
#define OFF_ARR  64                              // NBLK arrival flags, 128B spacing
#define OFF_REL  (OFF_ARR + NBLK * 32)           // NBLK release flags, 128B spacing
#define OFF_W1   (OFF_REL + NBLK * 32)           // 98304 f16 = 49152 floats (frag-linear hi)
#define OFF_W1L  (OFF_W1 + 49152)
#define OFF_W2   (OFF_W1L + 49152)
#define OFF_W2L  (OFF_W2 + 49152)                // built but not streamed in phase B
#define OFF_PART (OFF_W2L + 49152)               // NBLK x 1024 per-n partial |R|^2
#define OFF_FIN  (OFF_PART + NBLK * NRI)         // 1024 final sums

// dynamic LDS: zh/zl [64][96] f16 (24576B) + H [64][1024] f16 single-buffer (131072B)
#define SMEM_BYTES 155648

__global__ void ksetup(float* __restrict__ ws) {
    int t = threadIdx.x;
    if (t == 0)
        __hip_atomic_store((unsigned*)(ws + OFF_MAXKEY), 0u, __ATOMIC_RELAXED, __HIP_MEMORY_SCOPE_AGENT);
    for (int i = t; i < 2 * NBLK * 32; i += 256)
        __hip_atomic_store((unsigned*)(ws + OFF_ARR) + i, 0u, __ATOMIC_RELAXED, __HIP_MEMORY_SCOPE_AGENT);
}

// Build W1 (idft) and W2 (dft) in MFMA fragment-linear order, split f16 hi/lo.
// Frag element: value = M[k][n] with k = kc*32 + (lane>>4)*8 + j, n = nt*16 + (lane&15).
__global__ void kwf(float* __restrict__ ws) {
    int idx = blockIdx.x * 256 + threadIdx.x;
    if (idx >= 2 * 98304) return;
    int which = idx >= 98304;
    int id = which ? idx - 98304 : idx;
    int j = id & 7, lane = (id >> 3) & 63, rem = id >> 9;
    int k, n;
    if (!which) { int kc = rem % 3,  nt = rem / 3;  k = kc*32 + (lane>>4)*8 + j; n = nt*16 + (lane&15); }
    else        { int kc = rem & 31, nt = rem >> 5; k = kc*32 + (lane>>4)*8 + j; n = nt*16 + (lane&15); }
    int t, f, q, e;
    if (!which) { t = n >> 1; e = n & 1; f = k >> 1; q = k & 1; }
    else        { t = k >> 1; q = k & 1; f = n >> 1; e = n & 1; }
    int ft = (f * t) & (T - 1);
    float sv, cv;
    sincosf((float)ft * 0.012271846303085129f, &sv, &cv);   // 2*pi/512
    const float sc = 0.04419417382415922f;                  // 1/sqrt(512)
    cv *= sc; sv *= sc;
    float val;
    if (!which) val = (e == 0) ? (q == 0 ? cv : -sv) : (q == 0 ?  sv : cv);
    else        val = (e == 0) ? (q == 0 ? cv :  sv) : (q == 0 ? -sv : cv);
    f16 hi = (f16)val;
    f16 lo = (f16)(val - (float)hi);
    f16* H = (f16*)(ws + (which ? OFF_W2 : OFF_W1));
    f16* L = (f16*)(ws + (which ? OFF_W2L : OFF_W1L));
    H[id] = hi;
    L[id] = lo;
}

// Contention-free grid barrier (epoch-monotone): private arrival/release lines.
// Sweeper block alternates by epoch parity (0 / NBLK/2).
__device__ __forceinline__ void gbar2(float* __restrict__ ws, unsigned e) {
    asm volatile("s_waitcnt vmcnt(0)" ::: "memory");
    __syncthreads();
    const int tid = threadIdx.x;
    const unsigned swb = (e & 1u) ? (NBLK / 2) : 0;
    unsigned* __restrict__ Af = (unsigned*)(ws + OFF_ARR);
    unsigned* __restrict__ Rf = (unsigned*)(ws + OFF_REL);
    if (blockIdx.x == swb) {
        if (tid < 64) {
            bool ok;
            do {
                __builtin_amdgcn_s_sleep(1);
                ok = true;
#pragma unroll
                for (int s = 0; s < NBLK / 64; s++) {
                    unsigned b = s * 64 + tid;
                    unsigned v = __hip_atomic_load(&Af[b * 32], __ATOMIC_RELAXED, __HIP_MEMORY_SCOPE_AGENT);
                    ok = ok && (b == swb || v >= e);
                }
            } while (!__all(ok));
            asm volatile("" ::: "memory");
#pragma unroll
            for (int s = 0; s < NBLK / 64; s++) {
                unsigned b = s * 64 + tid;
                __hip_atomic_store(&Rf[b * 32], e, __ATOMIC_RELAXED, __HIP_MEMORY_SCOPE_AGENT);
            }
        }
        __syncthreads();
    } else {
        if (tid == 0) {
            __hip_atomic_store(&Af[blockIdx.x * 32], e, __ATOMIC_RELAXED, __HIP_MEMORY_SCOPE_AGENT);
            while (__hip_atomic_load(&Rf[blockIdx.x * 32], __ATOMIC_RELAXED, __HIP_MEMORY_SCOPE_AGENT) < e)
                __builtin_amdgcn_s_sleep(2);
            asm volatile("" ::: "memory");
        }
        __syncthreads();
    }
}

__device__ __forceinline__ void coh_store8(float* p, float a, float b) {
    unsigned long long v = ((unsigned long long)__float_as_uint(b) << 32) | __float_as_uint(a);
    (void)__hip_atomic_exchange((unsigned long long*)p, v, __ATOMIC_RELAXED, __HIP_MEMORY_SCOPE_AGENT);
}

// Persistent cooperative kernel. 256 blocks x 512 threads (8 waves), 64 rows/block.
// R^T[n][b] register-resident: 32 floatx4 per thread (128 AGPR). Wave w owns n in
// [w*128, w*128+128). C/D layout: lane holds (n = ntl*16 + q*4 + r, b = bt*16 + l15).
// REGISTER-PRESSURE SURGERY (unified 256 VGPR+AGPR cap at 8 waves/CU):
//  - phase A: bt-pair live-range split (Bh[2]/Bl[2] not [4]) under unroll 1
//  - phase B: ft-outer unroll-1 loop, single accf, epilogue fused per-ft
__global__ __launch_bounds__(512, 2) void kmain(const float* __restrict__ u,
                                                const float* __restrict__ S1,
                                                const float* __restrict__ S2,
                                                float* __restrict__ out,
                                                float* __restrict__ ws) {
    extern __shared__ char smem[];
    f16* zh = (f16*)smem;                        // [64][96] swizzled (fc&31) ^= (b&3)<<3
    f16* zl = zh + 64 * FC;
    f16* Hs = zl + 64 * FC;                      // [64][1024] swizzled col ^ ((row&7)<<3)
    __shared__ float smax[8];

    const int tid = threadIdx.x;
    const int w = tid >> 6;
    const int lane = tid & 63;
    const int q = lane >> 4;
    const int l15 = lane & 15;
    const int row0 = blockIdx.x * 64;
    const float s1 = S1[0], s2 = S2[0];

    unsigned epoch = 1;

    // ---- global max of u ----
    float m = -1e30f;
    for (int i = tid; i < 64 * FC; i += 512) m = fmaxf(m, u[(long)row0 * FC + i]);
#pragma unroll
    for (int s = 1; s < 64; s <<= 1) m = fmaxf(m, __shfl_xor(m, s, 64));
    if (lane == 0) smax[w] = m;
    __syncthreads();
    if (tid == 0) {
        float mm = smax[0];
#pragma unroll
        for (int i = 1; i < 8; i++) mm = fmaxf(mm, smax[i]);
        unsigned k = __float_as_uint(mm);
        k = (k & 0x80000000u) ? ~k : (k | 0x80000000u);
        atomicMax((unsigned*)(ws + OFF_MAXKEY), k);
    }
    gbar2(ws, epoch); epoch++;
    unsigned key = __hip_atomic_load((unsigned*)(ws + OFF_MAXKEY), __ATOMIC_RELAXED, __HIP_MEMORY_SCOPE_AGENT);
    unsigned ku = (key & 0x80000000u) ? (key ^ 0x80000000u) : ~key;
    const float gmax = fabsf(__uint_as_float(ku));
    const float sc_to = 5.0f / gmax;
    const float sc_from = gmax / 5.0f;

    // ---- z0 = sc_to * u, f16 hi/lo, swizzled ----
    for (int i = tid; i < 64 * FC; i += 512) {
        int b = i / FC, fc = i - b * FC;
        float z = sc_to * u[(long)row0 * FC + i];
        f16 h = (f16)z;
        int idx = b * FC + ((fc & ~31) | ((fc & 31) ^ ((b & 3) << 3)));
        zh[idx] = h;
        zl[idx] = (f16)(z - (float)h);
    }

    floatx4 R[32];
#pragma unroll
    for (int i = 0; i < 32; i++) R[i] = (floatx4){0.f, 0.f, 0.f, 0.f};

    const f16* __restrict__ w1h = (const f16*)(ws + OFF_W1);
    const f16* __restrict__ w1l = (const f16*)(ws + OFF_W1L);
    const f16* __restrict__ w2h = (const f16*)(ws + OFF_W2);

    const int brow = (w & 3) * 16 + l15;   // phase-B A-operand row (b)
    const int fh = (w >> 2) * 3;           // first of 3 f-tiles for this wave
    const int aswz = (brow & 7) << 3;
    const long hrow = (long)brow * NRI;

    float gcur = 0.0f;                     // g for n-pair {w*128+2*lane, +1}

#pragma unroll 1
    for (int l = 0; l < LAYERS; l++) {
        __syncthreads();   // z_lds ready (z0 or previous epilogue); H free for overwrite

        // ---- phase A: R = g_{l-1}*R + z @ W1   (C^T = W1^T(A) x z^T(B)) ----
        if (l > 0) {
#pragma unroll
            for (int ntl = 0; ntl < 8; ntl++) {
                float ga = __shfl(gcur, ntl * 8 + q * 2, 64);
                float gb = __shfl(gcur, ntl * 8 + q * 2 + 1, 64);
#pragma unroll
                for (int bt = 0; bt < 4; bt++) {
                    R[ntl * 4 + bt][0] *= ga;
                    R[ntl * 4 + bt][1] *= ga;
                    R[ntl * 4 + bt][2] *= gb;
                    R[ntl * 4 + bt][3] *= gb;
                }
            }
        }
#pragma unroll 1
        for (int kc = 0; kc < 3; kc++) {
#pragma unroll 1
            for (int g2 = 0; g2 < 2; g2++) {            // bt-pair split: only 2 B-frag pairs live
                half8 Bh[2], Bl[2];
#pragma unroll
                for (int bi = 0; bi < 2; bi++) {
                    int b = (g2 * 2 + bi) * 16 + l15;
                    int zi = b * FC + kc * 32 + ((q ^ (b & 3)) << 3);
                    Bh[bi] = *(const half8*)(zh + zi);
                    Bl[bi] = *(const half8*)(zl + zi);
                }
#pragma unroll
                for (int ntl = 0; ntl < 8; ntl++) {
                    int wi = (((w * 8 + ntl) * 3 + kc) * 64 + lane) * 8;
                    half8 Ah = *(const half8*)(w1h + wi);
                    half8 Al = *(const half8*)(w1l + wi);
#pragma unroll
                    for (int bi = 0; bi < 2; bi++) {
                        int bt = g2 * 2 + bi;
                        R[ntl*4+bt] = __builtin_amdgcn_mfma_f32_16x16x32_f16(Ah, Bh[bi], R[ntl*4+bt], 0, 0, 0);
                        R[ntl*4+bt] = __builtin_amdgcn_mfma_f32_16x16x32_f16(Ah, Bl[bi], R[ntl*4+bt], 0, 0, 0);
                        R[ntl*4+bt] = __builtin_amdgcn_mfma_f32_16x16x32_f16(Al, Bh[bi], R[ntl*4+bt], 0, 0, 0);
                    }
                }
            }
        }

        // ---- per-n partial sums of R^2 -> private block row (no contention) ----
        {
            float* part = ws + OFF_PART + (long)blockIdx.x * NRI;
#pragma unroll
            for (int ntl = 0; ntl < 8; ntl++) {
                floatx4 ps;
#pragma unroll
                for (int r = 0; r < 4; r++) {
                    float p = R[ntl*4+0][r] * R[ntl*4+0][r];
                    p = fmaf(R[ntl*4+1][r], R[ntl*4+1][r], p);
                    p = fmaf(R[ntl*4+2][r], R[ntl*4+2][r], p);
                    p = fmaf(R[ntl*4+3][r], R[ntl*4+3][r], p);
                    p += __shfl_xor(p, 1, 64);
                    p += __shfl_xor(p, 2, 64);
                    p += __shfl_xor(p, 4, 64);
                    p += __shfl_xor(p, 8, 64);
                    ps[r] = p;
                }
                if (l15 == 0) {
                    int n = w * 128 + ntl * 16 + q * 4;
                    coh_store8(part + n, ps[0], ps[1]);
                    coh_store8(part + n + 2, ps[2], ps[3]);
                }
            }
        }
        gbar2(ws, epoch); epoch++;

        // ---- combine: this block reduces n0..n0+3 over all 256 blocks (wave 0) ----
        if (w == 0) {
            const int n0 = blockIdx.x * 4;
            const float* pb = ws + OFF_PART;
            floatx4 cs = {0.f, 0.f, 0.f, 0.f};
#pragma unroll
            for (int s4 = 0; s4 < 4; s4++) {
                long off = (long)(s4 * 64 + lane) * NRI + n0;
                unsigned long long a = __hip_atomic_load((const unsigned long long*)(pb + off),
                                                         __ATOMIC_RELAXED, __HIP_MEMORY_SCOPE_AGENT);
                unsigned long long b = __hip_atomic_load((const unsigned long long*)(pb + off + 2),
                                                         __ATOMIC_RELAXED, __HIP_MEMORY_SCOPE_AGENT);
                cs[0] += __uint_as_float((unsigned)a);
                cs[1] += __uint_as_float((unsigned)(a >> 32));
                cs[2] += __uint_as_float((unsigned)b);
                cs[3] += __uint_as_float((unsigned)(b >> 32));
            }
#pragma unroll
            for (int sh = 1; sh < 64; sh <<= 1) {
                cs[0] += __shfl_xor(cs[0], sh, 64);
                cs[1] += __shfl_xor(cs[1], sh, 64);
                cs[2] += __shfl_xor(cs[2], sh, 64);
                cs[3] += __shfl_xor(cs[3], sh, 64);
            }
            if (lane == 0) {
                coh_store8(ws + OFF_FIN + n0, cs[0], cs[1]);
                coh_store8(ws + OFF_FIN + n0 + 2, cs[2], cs[3]);
            }
        }
        gbar2(ws, epoch); epoch++;

        // ---- readback + gate (wave-local; n-pair 2t,2t+1 shares one g) ----
        {
            int n = w * 128 + lane * 2;
            unsigned long long pv = __hip_atomic_load((const unsigned long long*)(ws + OFF_FIN + n),
                                                      __ATOMIC_RELAXED, __HIP_MEMORY_SCOPE_AGENT);
            float sa = __uint_as_float((unsigned)pv);
            float sb = __uint_as_float((unsigned)(pv >> 32));
            float rm = sqrtf((sa + sb) * (1.0f / 16384.0f));
            gcur = 1.0f / (1.0f + expf(-s1 * (rm - s2)));
        }

        // ---- phase B: stage H = g*R once (single f16, swizzled), one barrier ----
#pragma unroll
        for (int ntl = 0; ntl < 8; ntl++) {
            float ga = __shfl(gcur, ntl * 8 + q * 2, 64);
            float gb = __shfl(gcur, ntl * 8 + q * 2 + 1, 64);
            floatx4 g4 = {ga, ga, gb, gb};
            int col = w * 128 + ntl * 16 + q * 4;
#pragma unroll
            for (int bt = 0; bt < 4; bt++) {
                int row = bt * 16 + l15;
                half4 vh;
#pragma unroll
                for (int r = 0; r < 4; r++) vh[r] = (f16)(g4[r] * R[ntl * 4 + bt][r]);
                *(half4*)(Hs + row * NRI + (col ^ ((row & 7) << 3))) = vh;
            }
        }
        __syncthreads();

        // ---- barrier-free K loop, ft-outer (single live acc), epilogue fused ----
#pragma unroll 1
        for (int ft = 0; ft < 3; ft++) {
            floatx4 accf = {0.f, 0.f, 0.f, 0.f};
#pragma unroll 4
            for (int kg = 0; kg < 32; kg++) {
                half8 Ah = *(const half8*)(Hs + hrow + ((kg * 32 + q * 8) ^ aswz));
                int wi = (((fh + ft) * 32 + kg) * 64 + lane) * 8;
                half8 Wh = *(const half8*)(w2h + wi);
                accf = __builtin_amdgcn_mfma_f32_16x16x32_f16(Ah, Wh, accf, 0, 0, 0);
            }
            int fcg = (fh + ft) * 16 + l15;
            if (l < LAYERS - 1) {
#pragma unroll
                for (int r = 0; r < 4; r++) {
                    int b = (w & 3) * 16 + q * 4 + r;
                    float z = fmaf(sc_to, u[(long)(row0 + b) * FC + fcg], -accf[r]);
                    f16 h = (f16)z;
                    int idx = b * FC + ((fcg & ~31) | ((fcg & 31) ^ ((b & 3) << 3)));
                    zh[idx] = h;
                    zl[idx] = (f16)(z - (float)h);
                }
            } else {
#pragma unroll
                for (int r = 0; r < 4; r++) {
                    int b = (w & 3) * 16 + q * 4 + r;
                    out[(long)(row0 + b) * FC + fcg] = accf[r] * sc_from;
                }
            }
        }
    }
}

extern "C" void kernel_launch(void* const* d_in, const int* in_sizes, int n_in,
                              void* d_out, int out_size, void* d_ws, size_t ws_size,
                              hipStream_t stream) {
    (void)in_sizes; (void)n_in; (void)out_size; (void)ws_size;
    const float* u  = (const float*)d_in[0];
    const float* S1 = (const float*)d_in[1];
    const float* S2 = (const float*)d_in[2];
    float* out = (float*)d_out;
    float* ws  = (float*)d_ws;

    static int inited = 0;
    if (!inited) {
        hipFuncSetAttribute((const void*)kmain, hipFuncAttributeMaxDynamicSharedMemorySize, SMEM_BYTES);
        inited = 1;
    }

    ksetup<<<1, 256, 0, stream>>>(ws);
    kwf<<<768, 256, 0, stream>>>(ws);

    void* args[] = {(void*)&u, (void*)&S1, (void*)&S2, (void*)&out, (void*)&ws};
    hipLaunchCooperativeKernel((const void*)kmain, dim3(NBLK), dim3(512), args,
                               (unsigned)SMEM_BYTES, stream);
}

// Round 12
// 1435.517 us; speedup vs baseline: 1.2538x; 1.2538x over previous
//
#include <hip/hip_runtime.h>
#include <math.h>

#define NROWS 16384
#define FC 96
#define T 512
#define NRI 1024
#define LAYERS 16
#define NBLK 256

typedef _Float16 f16;
typedef _Float16 half8 __attribute__((ext_vector_type(8)));
typedef _Float16 half4 __attribute__((ext_vector_type(4)));
typedef float floatx4 __attribute__((ext_vector_type(4)));

// ws float offsets
#define OFF_MAXKEY 0                             // 1 uint (monotone-encoded float max)
#define OFF_ARR  64                              // NBLK arrival flags, 128B spacing
#define OFF_REL  (OFF_ARR + NBLK * 32)           // NBLK release flags, 128B spacing
#define OFF_W1   (OFF_REL + NBLK * 32)           // 98304 f16 = 49152 floats (frag-linear hi)
#define OFF_W1L  (OFF_W1 + 49152)
#define OFF_W2   (OFF_W1L + 49152)
#define OFF_W2L  (OFF_W2 + 49152)                // built but not streamed in phase B
#define OFF_PART (OFF_W2L + 49152)               // NBLK x 1024 per-n partial |R|^2
#define OFF_FIN  (OFF_PART + NBLK * NRI)         // 1024 final sums

// dynamic LDS: zh/zl [64][96] f16 (24576B) + H [64][1024] f16 single-buffer (131072B)
#define SMEM_BYTES 155648

__global__ void ksetup(float* __restrict__ ws) {
    int t = threadIdx.x;
    if (t == 0)
        __hip_atomic_store((unsigned*)(ws + OFF_MAXKEY), 0u, __ATOMIC_RELAXED, __HIP_MEMORY_SCOPE_AGENT);
    for (int i = t; i < 2 * NBLK * 32; i += 256)
        __hip_atomic_store((unsigned*)(ws + OFF_ARR) + i, 0u, __ATOMIC_RELAXED, __HIP_MEMORY_SCOPE_AGENT);
}

// Build W1 (idft) and W2 (dft) in MFMA fragment-linear order, split f16 hi/lo.
// Frag element: value = M[k][n] with k = kc*32 + (lane>>4)*8 + j, n = nt*16 + (lane&15).
__global__ void kwf(float* __restrict__ ws) {
    int idx = blockIdx.x * 256 + threadIdx.x;
    if (idx >= 2 * 98304) return;
    int which = idx >= 98304;
    int id = which ? idx - 98304 : idx;
    int j = id & 7, lane = (id >> 3) & 63, rem = id >> 9;
    int k, n;
    if (!which) { int kc = rem % 3,  nt = rem / 3;  k = kc*32 + (lane>>4)*8 + j; n = nt*16 + (lane&15); }
    else        { int kc = rem & 31, nt = rem >> 5; k = kc*32 + (lane>>4)*8 + j; n = nt*16 + (lane&15); }
    int t, f, q, e;
    if (!which) { t = n >> 1; e = n & 1; f = k >> 1; q = k & 1; }
    else        { t = k >> 1; q = k & 1; f = n >> 1; e = n & 1; }
    int ft = (f * t) & (T - 1);
    float sv, cv;
    sincosf((float)ft * 0.012271846303085129f, &sv, &cv);   // 2*pi/512
    const float sc = 0.04419417382415922f;                  // 1/sqrt(512)
    cv *= sc; sv *= sc;
    float val;
    if (!which) val = (e == 0) ? (q == 0 ? cv : -sv) : (q == 0 ?  sv : cv);
    else        val = (e == 0) ? (q == 0 ? cv :  sv) : (q == 0 ? -sv : cv);
    f16 hi = (f16)val;
    f16 lo = (f16)(val - (float)hi);
    f16* H = (f16*)(ws + (which ? OFF_W2 : OFF_W1));
    f16* L = (f16*)(ws + (which ? OFF_W2L : OFF_W1L));
    H[id] = hi;
    L[id] = lo;
}

// Contention-free grid barrier (epoch-monotone): private arrival/release lines.
// Sweeper block alternates by epoch parity (0 / NBLK/2).
__device__ __forceinline__ void gbar2(float* __restrict__ ws, unsigned e) {
    asm volatile("s_waitcnt vmcnt(0)" ::: "memory");
    __syncthreads();
    const int tid = threadIdx.x;
    const unsigned swb = (e & 1u) ? (NBLK / 2) : 0;
    unsigned* __restrict__ Af = (unsigned*)(ws + OFF_ARR);
    unsigned* __restrict__ Rf = (unsigned*)(ws + OFF_REL);
    if (blockIdx.x == swb) {
        if (tid < 64) {
            bool ok;
            do {
                __builtin_amdgcn_s_sleep(1);
                ok = true;
#pragma unroll
                for (int s = 0; s < NBLK / 64; s++) {
                    unsigned b = s * 64 + tid;
                    unsigned v = __hip_atomic_load(&Af[b * 32], __ATOMIC_RELAXED, __HIP_MEMORY_SCOPE_AGENT);
                    ok = ok && (b == swb || v >= e);
                }
            } while (!__all(ok));
            asm volatile("" ::: "memory");
#pragma unroll
            for (int s = 0; s < NBLK / 64; s++) {
                unsigned b = s * 64 + tid;
                __hip_atomic_store(&Rf[b * 32], e, __ATOMIC_RELAXED, __HIP_MEMORY_SCOPE_AGENT);
            }
        }
        __syncthreads();
    } else {
        if (tid == 0) {
            __hip_atomic_store(&Af[blockIdx.x * 32], e, __ATOMIC_RELAXED, __HIP_MEMORY_SCOPE_AGENT);
            while (__hip_atomic_load(&Rf[blockIdx.x * 32], __ATOMIC_RELAXED, __HIP_MEMORY_SCOPE_AGENT) < e)
                __builtin_amdgcn_s_sleep(2);
            asm volatile("" ::: "memory");
        }
        __syncthreads();
    }
}

__device__ __forceinline__ void coh_store8(float* p, float a, float b) {
    unsigned long long v = ((unsigned long long)__float_as_uint(b) << 32) | __float_as_uint(a);
    (void)__hip_atomic_exchange((unsigned long long*)p, v, __ATOMIC_RELAXED, __HIP_MEMORY_SCOPE_AGENT);
}

// Persistent cooperative kernel — r10 base (best: 1230 us), with the allreduce chain
// {parts -> bar -> combine -> bar -> gate} executed TWICE per layer as an in-situ
// IDEMPOTENT measurement of C_sync (parts are a pure function of R; second pass
// stores/derives bit-identical values). dur = base + 16*C_sync.
__global__ __launch_bounds__(512, 2) void kmain(const float* __restrict__ u,
                                                const float* __restrict__ S1,
                                                const float* __restrict__ S2,
                                                float* __restrict__ out,
                                                float* __restrict__ ws) {
    extern __shared__ char smem[];
    f16* zh = (f16*)smem;                        // [64][96] swizzled (fc&31) ^= (b&3)<<3
    f16* zl = zh + 64 * FC;
    f16* Hs = zl + 64 * FC;                      // [64][1024] swizzled col ^ ((row&7)<<3)
    __shared__ float smax[8];

    const int tid = threadIdx.x;
    const int w = tid >> 6;
    const int lane = tid & 63;
    const int q = lane >> 4;
    const int l15 = lane & 15;
    const int row0 = blockIdx.x * 64;
    const float s1 = S1[0], s2 = S2[0];

    unsigned epoch = 1;

    // ---- global max of u ----
    float m = -1e30f;
    for (int i = tid; i < 64 * FC; i += 512) m = fmaxf(m, u[(long)row0 * FC + i]);
#pragma unroll
    for (int s = 1; s < 64; s <<= 1) m = fmaxf(m, __shfl_xor(m, s, 64));
    if (lane == 0) smax[w] = m;
    __syncthreads();
    if (tid == 0) {
        float mm = smax[0];
#pragma unroll
        for (int i = 1; i < 8; i++) mm = fmaxf(mm, smax[i]);
        unsigned k = __float_as_uint(mm);
        k = (k & 0x80000000u) ? ~k : (k | 0x80000000u);
        atomicMax((unsigned*)(ws + OFF_MAXKEY), k);
    }
    gbar2(ws, epoch); epoch++;
    unsigned key = __hip_atomic_load((unsigned*)(ws + OFF_MAXKEY), __ATOMIC_RELAXED, __HIP_MEMORY_SCOPE_AGENT);
    unsigned ku = (key & 0x80000000u) ? (key ^ 0x80000000u) : ~key;
    const float gmax = fabsf(__uint_as_float(ku));
    const float sc_to = 5.0f / gmax;
    const float sc_from = gmax / 5.0f;

    // ---- z0 = sc_to * u, f16 hi/lo, swizzled ----
    for (int i = tid; i < 64 * FC; i += 512) {
        int b = i / FC, fc = i - b * FC;
        float z = sc_to * u[(long)row0 * FC + i];
        f16 h = (f16)z;
        int idx = b * FC + ((fc & ~31) | ((fc & 31) ^ ((b & 3) << 3)));
        zh[idx] = h;
        zl[idx] = (f16)(z - (float)h);
    }

    floatx4 R[32];
#pragma unroll
    for (int i = 0; i < 32; i++) R[i] = (floatx4){0.f, 0.f, 0.f, 0.f};

    const f16* __restrict__ w1h = (const f16*)(ws + OFF_W1);
    const f16* __restrict__ w1l = (const f16*)(ws + OFF_W1L);
    const f16* __restrict__ w2h = (const f16*)(ws + OFF_W2);

    const int brow = (w & 3) * 16 + l15;   // phase-B A-operand row (b)
    const int fh = (w >> 2) * 3;           // first of 3 f-tiles for this wave
    const int aswz = (brow & 7) << 3;
    const long hrow = (long)brow * NRI;

    float gcur = 0.0f;                     // g for n-pair {w*128+2*lane, +1}

#pragma unroll 1
    for (int l = 0; l < LAYERS; l++) {
        __syncthreads();   // z_lds ready (z0 or previous epilogue); H free for overwrite

        // ---- phase A: R = g_{l-1}*R + z @ W1   (C^T = W1^T(A) x z^T(B)) ----
        if (l > 0) {
#pragma unroll
            for (int ntl = 0; ntl < 8; ntl++) {
                float ga = __shfl(gcur, ntl * 8 + q * 2, 64);
                float gb = __shfl(gcur, ntl * 8 + q * 2 + 1, 64);
#pragma unroll
                for (int bt = 0; bt < 4; bt++) {
                    R[ntl * 4 + bt][0] *= ga;
                    R[ntl * 4 + bt][1] *= ga;
                    R[ntl * 4 + bt][2] *= gb;
                    R[ntl * 4 + bt][3] *= gb;
                }
            }
        }
#pragma unroll
        for (int kc = 0; kc < 3; kc++) {
            half8 Bh[4], Bl[4];
#pragma unroll
            for (int bt = 0; bt < 4; bt++) {
                int b = bt * 16 + l15;
                int zi = b * FC + kc * 32 + ((q ^ (b & 3)) << 3);
                Bh[bt] = *(const half8*)(zh + zi);
                Bl[bt] = *(const half8*)(zl + zi);
            }
#pragma unroll
            for (int ntl = 0; ntl < 8; ntl++) {
                int wi = (((w * 8 + ntl) * 3 + kc) * 64 + lane) * 8;
                half8 Ah = *(const half8*)(w1h + wi);
                half8 Al = *(const half8*)(w1l + wi);
#pragma unroll
                for (int bt = 0; bt < 4; bt++) {
                    R[ntl*4+bt] = __builtin_amdgcn_mfma_f32_16x16x32_f16(Ah, Bh[bt], R[ntl*4+bt], 0, 0, 0);
                    R[ntl*4+bt] = __builtin_amdgcn_mfma_f32_16x16x32_f16(Ah, Bl[bt], R[ntl*4+bt], 0, 0, 0);
                    R[ntl*4+bt] = __builtin_amdgcn_mfma_f32_16x16x32_f16(Al, Bh[bt], R[ntl*4+bt], 0, 0, 0);
                }
            }
        }

        // ==== allreduce chain, executed twice (idempotent) — C_sync measurement ====
#pragma unroll 1
        for (int rep = 0; rep < 2; rep++) {
            // ---- per-n partial sums of R^2 -> private block row (no contention) ----
            {
                float* part = ws + OFF_PART + (long)blockIdx.x * NRI;
#pragma unroll
                for (int ntl = 0; ntl < 8; ntl++) {
                    floatx4 ps;
#pragma unroll
                    for (int r = 0; r < 4; r++) {
                        float p = R[ntl*4+0][r] * R[ntl*4+0][r];
                        p = fmaf(R[ntl*4+1][r], R[ntl*4+1][r], p);
                        p = fmaf(R[ntl*4+2][r], R[ntl*4+2][r], p);
                        p = fmaf(R[ntl*4+3][r], R[ntl*4+3][r], p);
                        p += __shfl_xor(p, 1, 64);
                        p += __shfl_xor(p, 2, 64);
                        p += __shfl_xor(p, 4, 64);
                        p += __shfl_xor(p, 8, 64);
                        ps[r] = p;
                    }
                    if (l15 == 0) {
                        int n = w * 128 + ntl * 16 + q * 4;
                        coh_store8(part + n, ps[0], ps[1]);
                        coh_store8(part + n + 2, ps[2], ps[3]);
                    }
                }
            }
            gbar2(ws, epoch); epoch++;

            // ---- combine: this block reduces n0..n0+3 over all 256 blocks (wave 0) ----
            if (w == 0) {
                const int n0 = blockIdx.x * 4;
                const float* pb = ws + OFF_PART;
                floatx4 cs = {0.f, 0.f, 0.f, 0.f};
#pragma unroll
                for (int s4 = 0; s4 < 4; s4++) {
                    long off = (long)(s4 * 64 + lane) * NRI + n0;
                    unsigned long long a = __hip_atomic_load((const unsigned long long*)(pb + off),
                                                             __ATOMIC_RELAXED, __HIP_MEMORY_SCOPE_AGENT);
                    unsigned long long b = __hip_atomic_load((const unsigned long long*)(pb + off + 2),
                                                             __ATOMIC_RELAXED, __HIP_MEMORY_SCOPE_AGENT);
                    cs[0] += __uint_as_float((unsigned)a);
                    cs[1] += __uint_as_float((unsigned)(a >> 32));
                    cs[2] += __uint_as_float((unsigned)b);
                    cs[3] += __uint_as_float((unsigned)(b >> 32));
                }
#pragma unroll
                for (int sh = 1; sh < 64; sh <<= 1) {
                    cs[0] += __shfl_xor(cs[0], sh, 64);
                    cs[1] += __shfl_xor(cs[1], sh, 64);
                    cs[2] += __shfl_xor(cs[2], sh, 64);
                    cs[3] += __shfl_xor(cs[3], sh, 64);
                }
                if (lane == 0) {
                    coh_store8(ws + OFF_FIN + n0, cs[0], cs[1]);
                    coh_store8(ws + OFF_FIN + n0 + 2, cs[2], cs[3]);
                }
            }
            gbar2(ws, epoch); epoch++;

            // ---- readback + gate (wave-local; n-pair 2t,2t+1 shares one g) ----
            {
                int n = w * 128 + lane * 2;
                unsigned long long pv = __hip_atomic_load((const unsigned long long*)(ws + OFF_FIN + n),
                                                          __ATOMIC_RELAXED, __HIP_MEMORY_SCOPE_AGENT);
                float sa = __uint_as_float((unsigned)pv);
                float sb = __uint_as_float((unsigned)(pv >> 32));
                float rm = sqrtf((sa + sb) * (1.0f / 16384.0f));
                gcur = 1.0f / (1.0f + expf(-s1 * (rm - s2)));
            }
        }

        // ---- phase B: stage H = g*R once (single f16, swizzled), one barrier ----
#pragma unroll
        for (int ntl = 0; ntl < 8; ntl++) {
            float ga = __shfl(gcur, ntl * 8 + q * 2, 64);
            float gb = __shfl(gcur, ntl * 8 + q * 2 + 1, 64);
            floatx4 g4 = {ga, ga, gb, gb};
            int col = w * 128 + ntl * 16 + q * 4;
#pragma unroll
            for (int bt = 0; bt < 4; bt++) {
                int row = bt * 16 + l15;
                half4 vh;
#pragma unroll
                for (int r = 0; r < 4; r++) vh[r] = (f16)(g4[r] * R[ntl * 4 + bt][r]);
                *(half4*)(Hs + row * NRI + (col ^ ((row & 7) << 3))) = vh;
            }
        }
        __syncthreads();

        // ---- barrier-free K loop: h = H @ W2 (A = H f16, B = W2 single f16) ----
        floatx4 acc[3];
#pragma unroll
        for (int i = 0; i < 3; i++) acc[i] = (floatx4){0.f, 0.f, 0.f, 0.f};
#pragma unroll 4
        for (int kg = 0; kg < 32; kg++) {
            half8 Ah = *(const half8*)(Hs + hrow + ((kg * 32 + q * 8) ^ aswz));
#pragma unroll
            for (int ft = 0; ft < 3; ft++) {
                int wi = (((fh + ft) * 32 + kg) * 64 + lane) * 8;
                half8 Wh = *(const half8*)(w2h + wi);
                acc[ft] = __builtin_amdgcn_mfma_f32_16x16x32_f16(Ah, Wh, acc[ft], 0, 0, 0);
            }
        }

        // ---- epilogue: z = u*sc_to - h  (or final out = h*sc_from) ----
        if (l < LAYERS - 1) {
#pragma unroll
            for (int ft = 0; ft < 3; ft++) {
                int fcg = (fh + ft) * 16 + l15;
#pragma unroll
                for (int r = 0; r < 4; r++) {
                    int b = (w & 3) * 16 + q * 4 + r;
                    float z = fmaf(sc_to, u[(long)(row0 + b) * FC + fcg], -acc[ft][r]);
                    f16 h = (f16)z;
                    int idx = b * FC + ((fcg & ~31) | ((fcg & 31) ^ ((b & 3) << 3)));
                    zh[idx] = h;
                    zl[idx] = (f16)(z - (float)h);
                }
            }
        } else {
#pragma unroll
            for (int ft = 0; ft < 3; ft++) {
                int fcg = (fh + ft) * 16 + l15;
#pragma unroll
                for (int r = 0; r < 4; r++) {
                    int b = (w & 3) * 16 + q * 4 + r;
                    out[(long)(row0 + b) * FC + fcg] = acc[ft][r] * sc_from;
                }
            }
        }
    }
}

extern "C" void kernel_launch(void* const* d_in, const int* in_sizes, int n_in,
                              void* d_out, int out_size, void* d_ws, size_t ws_size,
                              hipStream_t stream) {
    (void)in_sizes; (void)n_in; (void)out_size; (void)ws_size;
    const float* u  = (const float*)d_in[0];
    const float* S1 = (const float*)d_in[1];
    const float* S2 = (const float*)d_in[2];
    float* out = (float*)d_out;
    float* ws  = (float*)d_ws;

    static int inited = 0;
    if (!inited) {
        hipFuncSetAttribute((const void*)kmain, hipFuncAttributeMaxDynamicSharedMemorySize, SMEM_BYTES);
        inited = 1;
    }

    ksetup<<<1, 256, 0, stream>>>(ws);
    kwf<<<768, 256, 0, stream>>>(ws);

    void* args[] = {(void*)&u, (void*)&S1, (void*)&S2, (void*)&out, (void*)&ws};
    hipLaunchCooperativeKernel((const void*)kmain, dim3(NBLK), dim3(512), args,
                               (unsigned)SMEM_BYTES, stream);
}

// Round 13
// 1176.856 us; speedup vs baseline: 1.5294x; 1.2198x over previous
//
#include <hip/hip_runtime.h>
#include <math.h>

#define NROWS 16384
#define FC 96
#define T 512
#define NRI 1024
#define LAYERS 16
#define NBLK 256

typedef _Float16 f16;
typedef _Float16 half8 __attribute__((ext_vector_type(8)));
typedef _Float16 half4 __attribute__((ext_vector_type(4)));
typedef float floatx4 __attribute__((ext_vector_type(4)));

// ws float offsets
#define OFF_MAXKEY 0                             // 1 uint (monotone-encoded float max)
#define OFF_ARR  64                              // NBLK arrival flags, 128B spacing
#define OFF_REL  (OFF_ARR + NBLK * 32)           // NBLK release flags, 128B spacing
#define OFF_W1   (OFF_REL + NBLK * 32)           // 98304 f16 = 49152 floats (frag-linear hi)
#define OFF_W1L  (OFF_W1 + 49152)                // built but not streamed (W1-lo dropped)
#define OFF_W2   (OFF_W1L + 49152)
#define OFF_W2L  (OFF_W2 + 49152)                // built but not streamed (W2-lo dropped)
#define OFF_PART (OFF_W2L + 49152)               // NBLK x 1024 per-n partial |R|^2
#define OFF_FIN  (OFF_PART + NBLK * NRI)         // 1024 final sums

// dynamic LDS: zh/zl [64][96] f16 (24576B) + H [64][1024] f16 single-buffer (131072B)
#define SMEM_BYTES 155648

__global__ void ksetup(float* __restrict__ ws) {
    int t = threadIdx.x;
    if (t == 0)
        __hip_atomic_store((unsigned*)(ws + OFF_MAXKEY), 0u, __ATOMIC_RELAXED, __HIP_MEMORY_SCOPE_AGENT);
    for (int i = t; i < 2 * NBLK * 32; i += 256)
        __hip_atomic_store((unsigned*)(ws + OFF_ARR) + i, 0u, __ATOMIC_RELAXED, __HIP_MEMORY_SCOPE_AGENT);
}

// Build W1 (idft) and W2 (dft) in MFMA fragment-linear order, split f16 hi/lo.
// Frag element: value = M[k][n] with k = kc*32 + (lane>>4)*8 + j, n = nt*16 + (lane&15).
__global__ void kwf(float* __restrict__ ws) {
    int idx = blockIdx.x * 256 + threadIdx.x;
    if (idx >= 2 * 98304) return;
    int which = idx >= 98304;
    int id = which ? idx - 98304 : idx;
    int j = id & 7, lane = (id >> 3) & 63, rem = id >> 9;
    int k, n;
    if (!which) { int kc = rem % 3,  nt = rem / 3;  k = kc*32 + (lane>>4)*8 + j; n = nt*16 + (lane&15); }
    else        { int kc = rem & 31, nt = rem >> 5; k = kc*32 + (lane>>4)*8 + j; n = nt*16 + (lane&15); }
    int t, f, q, e;
    if (!which) { t = n >> 1; e = n & 1; f = k >> 1; q = k & 1; }
    else        { t = k >> 1; q = k & 1; f = n >> 1; e = n & 1; }
    int ft = (f * t) & (T - 1);
    float sv, cv;
    sincosf((float)ft * 0.012271846303085129f, &sv, &cv);   // 2*pi/512
    const float sc = 0.04419417382415922f;                  // 1/sqrt(512)
    cv *= sc; sv *= sc;
    float val;
    if (!which) val = (e == 0) ? (q == 0 ? cv : -sv) : (q == 0 ?  sv : cv);
    else        val = (e == 0) ? (q == 0 ? cv :  sv) : (q == 0 ? -sv : cv);
    f16 hi = (f16)val;
    f16 lo = (f16)(val - (float)hi);
    f16* H = (f16*)(ws + (which ? OFF_W2 : OFF_W1));
    f16* L = (f16*)(ws + (which ? OFF_W2L : OFF_W1L));
    H[id] = hi;
    L[id] = lo;
}

// Contention-free grid barrier (epoch-monotone): private arrival/release lines.
// Sweeper block alternates by epoch parity (0 / NBLK/2).
__device__ __forceinline__ void gbar2(float* __restrict__ ws, unsigned e) {
    asm volatile("s_waitcnt vmcnt(0)" ::: "memory");
    __syncthreads();
    const int tid = threadIdx.x;
    const unsigned swb = (e & 1u) ? (NBLK / 2) : 0;
    unsigned* __restrict__ Af = (unsigned*)(ws + OFF_ARR);
    unsigned* __restrict__ Rf = (unsigned*)(ws + OFF_REL);
    if (blockIdx.x == swb) {
        if (tid < 64) {
            bool ok;
            do {
                __builtin_amdgcn_s_sleep(1);
                ok = true;
#pragma unroll
                for (int s = 0; s < NBLK / 64; s++) {
                    unsigned b = s * 64 + tid;
                    unsigned v = __hip_atomic_load(&Af[b * 32], __ATOMIC_RELAXED, __HIP_MEMORY_SCOPE_AGENT);
                    ok = ok && (b == swb || v >= e);
                }
            } while (!__all(ok));
            asm volatile("" ::: "memory");
#pragma unroll
            for (int s = 0; s < NBLK / 64; s++) {
                unsigned b = s * 64 + tid;
                __hip_atomic_store(&Rf[b * 32], e, __ATOMIC_RELAXED, __HIP_MEMORY_SCOPE_AGENT);
            }
        }
        __syncthreads();
    } else {
        if (tid == 0) {
            __hip_atomic_store(&Af[blockIdx.x * 32], e, __ATOMIC_RELAXED, __HIP_MEMORY_SCOPE_AGENT);
            while (__hip_atomic_load(&Rf[blockIdx.x * 32], __ATOMIC_RELAXED, __HIP_MEMORY_SCOPE_AGENT) < e)
                __builtin_amdgcn_s_sleep(2);
            asm volatile("" ::: "memory");
        }
        __syncthreads();
    }
}

__device__ __forceinline__ void coh_store8(float* p, float a, float b) {
    unsigned long long v = ((unsigned long long)__float_as_uint(b) << 32) | __float_as_uint(a);
    (void)__hip_atomic_exchange((unsigned long long*)p, v, __ATOMIC_RELAXED, __HIP_MEMORY_SCOPE_AGENT);
}

// Persistent cooperative kernel. 256 blocks x 512 threads (8 waves), 64 rows/block.
// R^T[n][b] register-resident: 32 floatx4 per thread. Wave w owns n in [w*128, w*128+128).
// C/D layout: lane holds (n = ntl*16 + q*4 + r, b = bt*16 + l15).
// Numerics: z is f16 hi+lo; W1 and W2 are SINGLE f16 (lo terms dropped — W entries
// <= 1/sqrt(512) so per-entry err <= 1.1e-5; measured headroom 4x at threshold 0.031).
// Phase A: 2 MFMA per frag (Ah*Bh + Ah*Bl). Phase B: 1 MFMA per frag.
__global__ __launch_bounds__(512, 2) void kmain(const float* __restrict__ u,
                                                const float* __restrict__ S1,
                                                const float* __restrict__ S2,
                                                float* __restrict__ out,
                                                float* __restrict__ ws) {
    extern __shared__ char smem[];
    f16* zh = (f16*)smem;                        // [64][96] swizzled (fc&31) ^= (b&3)<<3
    f16* zl = zh + 64 * FC;
    f16* Hs = zl + 64 * FC;                      // [64][1024] swizzled col ^ ((row&7)<<3)
    __shared__ float smax[8];

    const int tid = threadIdx.x;
    const int w = tid >> 6;
    const int lane = tid & 63;
    const int q = lane >> 4;
    const int l15 = lane & 15;
    const int row0 = blockIdx.x * 64;
    const float s1 = S1[0], s2 = S2[0];

    unsigned epoch = 1;

    // ---- global max of u ----
    float m = -1e30f;
    for (int i = tid; i < 64 * FC; i += 512) m = fmaxf(m, u[(long)row0 * FC + i]);
#pragma unroll
    for (int s = 1; s < 64; s <<= 1) m = fmaxf(m, __shfl_xor(m, s, 64));
    if (lane == 0) smax[w] = m;
    __syncthreads();
    if (tid == 0) {
        float mm = smax[0];
#pragma unroll
        for (int i = 1; i < 8; i++) mm = fmaxf(mm, smax[i]);
        unsigned k = __float_as_uint(mm);
        k = (k & 0x80000000u) ? ~k : (k | 0x80000000u);
        atomicMax((unsigned*)(ws + OFF_MAXKEY), k);
    }
    gbar2(ws, epoch); epoch++;
    unsigned key = __hip_atomic_load((unsigned*)(ws + OFF_MAXKEY), __ATOMIC_RELAXED, __HIP_MEMORY_SCOPE_AGENT);
    unsigned ku = (key & 0x80000000u) ? (key ^ 0x80000000u) : ~key;
    const float gmax = fabsf(__uint_as_float(ku));
    const float sc_to = 5.0f / gmax;
    const float sc_from = gmax / 5.0f;

    // ---- z0 = sc_to * u, f16 hi/lo, swizzled ----
    for (int i = tid; i < 64 * FC; i += 512) {
        int b = i / FC, fc = i - b * FC;
        float z = sc_to * u[(long)row0 * FC + i];
        f16 h = (f16)z;
        int idx = b * FC + ((fc & ~31) | ((fc & 31) ^ ((b & 3) << 3)));
        zh[idx] = h;
        zl[idx] = (f16)(z - (float)h);
    }

    floatx4 R[32];
#pragma unroll
    for (int i = 0; i < 32; i++) R[i] = (floatx4){0.f, 0.f, 0.f, 0.f};

    const f16* __restrict__ w1h = (const f16*)(ws + OFF_W1);
    const f16* __restrict__ w2h = (const f16*)(ws + OFF_W2);

    const int brow = (w & 3) * 16 + l15;   // phase-B A-operand row (b)
    const int fh = (w >> 2) * 3;           // first of 3 f-tiles for this wave
    const int aswz = (brow & 7) << 3;
    const long hrow = (long)brow * NRI;

    float gcur = 0.0f;                     // g for n-pair {w*128+2*lane, +1}

#pragma unroll 1
    for (int l = 0; l < LAYERS; l++) {
        __syncthreads();   // z_lds ready (z0 or previous epilogue); H free for overwrite

        // ---- phase A: R = g_{l-1}*R + z @ W1   (C^T = W1^T(A) x z^T(B)) ----
        if (l > 0) {
#pragma unroll
            for (int ntl = 0; ntl < 8; ntl++) {
                float ga = __shfl(gcur, ntl * 8 + q * 2, 64);
                float gb = __shfl(gcur, ntl * 8 + q * 2 + 1, 64);
#pragma unroll
                for (int bt = 0; bt < 4; bt++) {
                    R[ntl * 4 + bt][0] *= ga;
                    R[ntl * 4 + bt][1] *= ga;
                    R[ntl * 4 + bt][2] *= gb;
                    R[ntl * 4 + bt][3] *= gb;
                }
            }
        }
#pragma unroll
        for (int kc = 0; kc < 3; kc++) {
            half8 Bh[4], Bl[4];
#pragma unroll
            for (int bt = 0; bt < 4; bt++) {
                int b = bt * 16 + l15;
                int zi = b * FC + kc * 32 + ((q ^ (b & 3)) << 3);
                Bh[bt] = *(const half8*)(zh + zi);
                Bl[bt] = *(const half8*)(zl + zi);
            }
#pragma unroll
            for (int ntl = 0; ntl < 8; ntl++) {
                int wi = (((w * 8 + ntl) * 3 + kc) * 64 + lane) * 8;
                half8 Ah = *(const half8*)(w1h + wi);
#pragma unroll
                for (int bt = 0; bt < 4; bt++) {
                    R[ntl*4+bt] = __builtin_amdgcn_mfma_f32_16x16x32_f16(Ah, Bh[bt], R[ntl*4+bt], 0, 0, 0);
                    R[ntl*4+bt] = __builtin_amdgcn_mfma_f32_16x16x32_f16(Ah, Bl[bt], R[ntl*4+bt], 0, 0, 0);
                }
            }
        }

        // ---- per-n partial sums of R^2 -> private block row (no contention) ----
        {
            float* part = ws + OFF_PART + (long)blockIdx.x * NRI;
#pragma unroll
            for (int ntl = 0; ntl < 8; ntl++) {
                floatx4 ps;
#pragma unroll
                for (int r = 0; r < 4; r++) {
                    float p = R[ntl*4+0][r] * R[ntl*4+0][r];
                    p = fmaf(R[ntl*4+1][r], R[ntl*4+1][r], p);
                    p = fmaf(R[ntl*4+2][r], R[ntl*4+2][r], p);
                    p = fmaf(R[ntl*4+3][r], R[ntl*4+3][r], p);
                    p += __shfl_xor(p, 1, 64);
                    p += __shfl_xor(p, 2, 64);
                    p += __shfl_xor(p, 4, 64);
                    p += __shfl_xor(p, 8, 64);
                    ps[r] = p;
                }
                if (l15 == 0) {
                    int n = w * 128 + ntl * 16 + q * 4;
                    coh_store8(part + n, ps[0], ps[1]);
                    coh_store8(part + n + 2, ps[2], ps[3]);
                }
            }
        }
        gbar2(ws, epoch); epoch++;

        // ---- combine: this block reduces n0..n0+3 over all 256 blocks (wave 0) ----
        if (w == 0) {
            const int n0 = blockIdx.x * 4;
            const float* pb = ws + OFF_PART;
            floatx4 cs = {0.f, 0.f, 0.f, 0.f};
#pragma unroll
            for (int s4 = 0; s4 < 4; s4++) {
                long off = (long)(s4 * 64 + lane) * NRI + n0;
                unsigned long long a = __hip_atomic_load((const unsigned long long*)(pb + off),
                                                         __ATOMIC_RELAXED, __HIP_MEMORY_SCOPE_AGENT);
                unsigned long long b = __hip_atomic_load((const unsigned long long*)(pb + off + 2),
                                                         __ATOMIC_RELAXED, __HIP_MEMORY_SCOPE_AGENT);
                cs[0] += __uint_as_float((unsigned)a);
                cs[1] += __uint_as_float((unsigned)(a >> 32));
                cs[2] += __uint_as_float((unsigned)b);
                cs[3] += __uint_as_float((unsigned)(b >> 32));
            }
#pragma unroll
            for (int sh = 1; sh < 64; sh <<= 1) {
                cs[0] += __shfl_xor(cs[0], sh, 64);
                cs[1] += __shfl_xor(cs[1], sh, 64);
                cs[2] += __shfl_xor(cs[2], sh, 64);
                cs[3] += __shfl_xor(cs[3], sh, 64);
            }
            if (lane == 0) {
                coh_store8(ws + OFF_FIN + n0, cs[0], cs[1]);
                coh_store8(ws + OFF_FIN + n0 + 2, cs[2], cs[3]);
            }
        }
        gbar2(ws, epoch); epoch++;

        // ---- readback + gate (wave-local; n-pair 2t,2t+1 shares one g) ----
        {
            int n = w * 128 + lane * 2;
            unsigned long long pv = __hip_atomic_load((const unsigned long long*)(ws + OFF_FIN + n),
                                                      __ATOMIC_RELAXED, __HIP_MEMORY_SCOPE_AGENT);
            float sa = __uint_as_float((unsigned)pv);
            float sb = __uint_as_float((unsigned)(pv >> 32));
            float rm = sqrtf((sa + sb) * (1.0f / 16384.0f));
            gcur = 1.0f / (1.0f + expf(-s1 * (rm - s2)));
        }

        // ---- phase B: stage H = g*R once (single f16, swizzled), one barrier ----
#pragma unroll
        for (int ntl = 0; ntl < 8; ntl++) {
            float ga = __shfl(gcur, ntl * 8 + q * 2, 64);
            float gb = __shfl(gcur, ntl * 8 + q * 2 + 1, 64);
            floatx4 g4 = {ga, ga, gb, gb};
            int col = w * 128 + ntl * 16 + q * 4;
#pragma unroll
            for (int bt = 0; bt < 4; bt++) {
                int row = bt * 16 + l15;
                half4 vh;
#pragma unroll
                for (int r = 0; r < 4; r++) vh[r] = (f16)(g4[r] * R[ntl * 4 + bt][r]);
                *(half4*)(Hs + row * NRI + (col ^ ((row & 7) << 3))) = vh;
            }
        }
        __syncthreads();

        // ---- barrier-free K loop: h = H @ W2 (A = H f16, B = W2 single f16) ----
        floatx4 acc[3];
#pragma unroll
        for (int i = 0; i < 3; i++) acc[i] = (floatx4){0.f, 0.f, 0.f, 0.f};
#pragma unroll 4
        for (int kg = 0; kg < 32; kg++) {
            half8 Ah = *(const half8*)(Hs + hrow + ((kg * 32 + q * 8) ^ aswz));
#pragma unroll
            for (int ft = 0; ft < 3; ft++) {
                int wi = (((fh + ft) * 32 + kg) * 64 + lane) * 8;
                half8 Wh = *(const half8*)(w2h + wi);
                acc[ft] = __builtin_amdgcn_mfma_f32_16x16x32_f16(Ah, Wh, acc[ft], 0, 0, 0);
            }
        }

        // ---- epilogue: z = u*sc_to - h  (or final out = h*sc_from) ----
        if (l < LAYERS - 1) {
#pragma unroll
            for (int ft = 0; ft < 3; ft++) {
                int fcg = (fh + ft) * 16 + l15;
#pragma unroll
                for (int r = 0; r < 4; r++) {
                    int b = (w & 3) * 16 + q * 4 + r;
                    float z = fmaf(sc_to, u[(long)(row0 + b) * FC + fcg], -acc[ft][r]);
                    f16 h = (f16)z;
                    int idx = b * FC + ((fcg & ~31) | ((fcg & 31) ^ ((b & 3) << 3)));
                    zh[idx] = h;
                    zl[idx] = (f16)(z - (float)h);
                }
            }
        } else {
#pragma unroll
            for (int ft = 0; ft < 3; ft++) {
                int fcg = (fh + ft) * 16 + l15;
#pragma unroll
                for (int r = 0; r < 4; r++) {
                    int b = (w & 3) * 16 + q * 4 + r;
                    out[(long)(row0 + b) * FC + fcg] = acc[ft][r] * sc_from;
                }
            }
        }
    }
}

extern "C" void kernel_launch(void* const* d_in, const int* in_sizes, int n_in,
                              void* d_out, int out_size, void* d_ws, size_t ws_size,
                              hipStream_t stream) {
    (void)in_sizes; (void)n_in; (void)out_size; (void)ws_size;
    const float* u  = (const float*)d_in[0];
    const float* S1 = (const float*)d_in[1];
    const float* S2 = (const float*)d_in[2];
    float* out = (float*)d_out;
    float* ws  = (float*)d_ws;

    static int inited = 0;
    if (!inited) {
        hipFuncSetAttribute((const void*)kmain, hipFuncAttributeMaxDynamicSharedMemorySize, SMEM_BYTES);
        inited = 1;
    }

    ksetup<<<1, 256, 0, stream>>>(ws);
    kwf<<<768, 256, 0, stream>>>(ws);

    void* args[] = {(void*)&u, (void*)&S1, (void*)&S2, (void*)&out, (void*)&ws};
    hipLaunchCooperativeKernel((const void*)kmain, dim3(NBLK), dim3(512), args,
                               (unsigned)SMEM_BYTES, stream);
}

// Round 14
// 1132.478 us; speedup vs baseline: 1.5893x; 1.0392x over previous
//
#include <hip/hip_runtime.h>
#include <math.h>

#define NROWS 16384
#define FC 96
#define T 512
#define NRI 1024
#define LAYERS 16
#define NBLK 256

typedef _Float16 f16;
typedef _Float16 half8 __attribute__((ext_vector_type(8)));
typedef _Float16 half4 __attribute__((ext_vector_type(4)));
typedef float floatx4 __attribute__((ext_vector_type(4)));

// ws float offsets
#define OFF_MAXKEY 0                             // 1 uint (monotone-encoded float max)
#define OFF_ARR  64                              // NBLK arrival flags, 128B spacing
#define OFF_REL  (OFF_ARR + NBLK * 32)           // NBLK release flags, 128B spacing
#define OFF_W1   (OFF_REL + NBLK * 32)           // 98304 f16 = 49152 floats (frag-linear hi)
#define OFF_W1L  (OFF_W1 + 49152)                // built but not streamed (lo dropped)
#define OFF_W2   (OFF_W1L + 49152)
#define OFF_W2L  (OFF_W2 + 49152)                // built but not streamed (lo dropped)
#define OFF_PART (OFF_W2L + 49152)               // NBLK x 1024 per-n partial |R|^2
#define OFF_FIN  (OFF_PART + NBLK * NRI)         // 1024 final sums

// dynamic LDS: zh [64][96] f16 (12288B) + H [64][1024] f16 single-buffer (131072B)
#define SMEM_BYTES 143360

__global__ void ksetup(float* __restrict__ ws) {
    int t = threadIdx.x;
    if (t == 0)
        __hip_atomic_store((unsigned*)(ws + OFF_MAXKEY), 0u, __ATOMIC_RELAXED, __HIP_MEMORY_SCOPE_AGENT);
    for (int i = t; i < 2 * NBLK * 32; i += 256)
        __hip_atomic_store((unsigned*)(ws + OFF_ARR) + i, 0u, __ATOMIC_RELAXED, __HIP_MEMORY_SCOPE_AGENT);
}

// Build W1 (idft) and W2 (dft) in MFMA fragment-linear order, split f16 hi/lo.
// Frag element: value = M[k][n] with k = kc*32 + (lane>>4)*8 + j, n = nt*16 + (lane&15).
__global__ void kwf(float* __restrict__ ws) {
    int idx = blockIdx.x * 256 + threadIdx.x;
    if (idx >= 2 * 98304) return;
    int which = idx >= 98304;
    int id = which ? idx - 98304 : idx;
    int j = id & 7, lane = (id >> 3) & 63, rem = id >> 9;
    int k, n;
    if (!which) { int kc = rem % 3,  nt = rem / 3;  k = kc*32 + (lane>>4)*8 + j; n = nt*16 + (lane&15); }
    else        { int kc = rem & 31, nt = rem >> 5; k = kc*32 + (lane>>4)*8 + j; n = nt*16 + (lane&15); }
    int t, f, q, e;
    if (!which) { t = n >> 1; e = n & 1; f = k >> 1; q = k & 1; }
    else        { t = k >> 1; q = k & 1; f = n >> 1; e = n & 1; }
    int ft = (f * t) & (T - 1);
    float sv, cv;
    sincosf((float)ft * 0.012271846303085129f, &sv, &cv);   // 2*pi/512
    const float sc = 0.04419417382415922f;                  // 1/sqrt(512)
    cv *= sc; sv *= sc;
    float val;
    if (!which) val = (e == 0) ? (q == 0 ? cv : -sv) : (q == 0 ?  sv : cv);
    else        val = (e == 0) ? (q == 0 ? cv :  sv) : (q == 0 ? -sv : cv);
    f16 hi = (f16)val;
    f16 lo = (f16)(val - (float)hi);
    f16* H = (f16*)(ws + (which ? OFF_W2 : OFF_W1));
    f16* L = (f16*)(ws + (which ? OFF_W2L : OFF_W1L));
    H[id] = hi;
    L[id] = lo;
}

// Contention-free grid barrier (epoch-monotone): private arrival/release lines.
// Sweeper block alternates by epoch parity (0 / NBLK/2).
__device__ __forceinline__ void gbar2(float* __restrict__ ws, unsigned e) {
    asm volatile("s_waitcnt vmcnt(0)" ::: "memory");
    __syncthreads();
    const int tid = threadIdx.x;
    const unsigned swb = (e & 1u) ? (NBLK / 2) : 0;
    unsigned* __restrict__ Af = (unsigned*)(ws + OFF_ARR);
    unsigned* __restrict__ Rf = (unsigned*)(ws + OFF_REL);
    if (blockIdx.x == swb) {
        if (tid < 64) {
            bool ok;
            do {
                __builtin_amdgcn_s_sleep(1);
                ok = true;
#pragma unroll
                for (int s = 0; s < NBLK / 64; s++) {
                    unsigned b = s * 64 + tid;
                    unsigned v = __hip_atomic_load(&Af[b * 32], __ATOMIC_RELAXED, __HIP_MEMORY_SCOPE_AGENT);
                    ok = ok && (b == swb || v >= e);
                }
            } while (!__all(ok));
            asm volatile("" ::: "memory");
#pragma unroll
            for (int s = 0; s < NBLK / 64; s++) {
                unsigned b = s * 64 + tid;
                __hip_atomic_store(&Rf[b * 32], e, __ATOMIC_RELAXED, __HIP_MEMORY_SCOPE_AGENT);
            }
        }
        __syncthreads();
    } else {
        if (tid == 0) {
            __hip_atomic_store(&Af[blockIdx.x * 32], e, __ATOMIC_RELAXED, __HIP_MEMORY_SCOPE_AGENT);
            while (__hip_atomic_load(&Rf[blockIdx.x * 32], __ATOMIC_RELAXED, __HIP_MEMORY_SCOPE_AGENT) < e)
                __builtin_amdgcn_s_sleep(2);
            asm volatile("" ::: "memory");
        }
        __syncthreads();
    }
}

__device__ __forceinline__ void coh_store8(float* p, float a, float b) {
    unsigned long long v = ((unsigned long long)__float_as_uint(b) << 32) | __float_as_uint(a);
    (void)__hip_atomic_exchange((unsigned long long*)p, v, __ATOMIC_RELAXED, __HIP_MEMORY_SCOPE_AGENT);
}

// Persistent cooperative kernel. 256 blocks x 512 threads (8 waves), 64 rows/block.
// R^T[n][b] register-resident: 32 floatx4 per thread. Wave w owns n in [w*128, w*128+128).
// C/D layout: lane holds (n = ntl*16 + q*4 + r, b = bt*16 + l15).
// Numerics: z, W1, W2, H all SINGLE f16 (hi/lo splits dropped r8/r10/r13/r14 —
// anchor: r8's H-lo drop (K=1024) left absmax bit-identical; W entries <= 1/sqrt(512)).
// Phase A: 1 MFMA per frag. Phase B: 1 MFMA per frag.
__global__ __launch_bounds__(512, 2) void kmain(const float* __restrict__ u,
                                                const float* __restrict__ S1,
                                                const float* __restrict__ S2,
                                                float* __restrict__ out,
                                                float* __restrict__ ws) {
    extern __shared__ char smem[];
    f16* zh = (f16*)smem;                        // [64][96] swizzled (fc&31) ^= (b&3)<<3
    f16* Hs = zh + 64 * FC;                      // [64][1024] swizzled col ^ ((row&7)<<3)
    __shared__ float smax[8];

    const int tid = threadIdx.x;
    const int w = tid >> 6;
    const int lane = tid & 63;
    const int q = lane >> 4;
    const int l15 = lane & 15;
    const int row0 = blockIdx.x * 64;
    const float s1 = S1[0], s2 = S2[0];

    unsigned epoch = 1;

    // ---- global max of u ----
    float m = -1e30f;
    for (int i = tid; i < 64 * FC; i += 512) m = fmaxf(m, u[(long)row0 * FC + i]);
#pragma unroll
    for (int s = 1; s < 64; s <<= 1) m = fmaxf(m, __shfl_xor(m, s, 64));
    if (lane == 0) smax[w] = m;
    __syncthreads();
    if (tid == 0) {
        float mm = smax[0];
#pragma unroll
        for (int i = 1; i < 8; i++) mm = fmaxf(mm, smax[i]);
        unsigned k = __float_as_uint(mm);
        k = (k & 0x80000000u) ? ~k : (k | 0x80000000u);
        atomicMax((unsigned*)(ws + OFF_MAXKEY), k);
    }
    gbar2(ws, epoch); epoch++;
    unsigned key = __hip_atomic_load((unsigned*)(ws + OFF_MAXKEY), __ATOMIC_RELAXED, __HIP_MEMORY_SCOPE_AGENT);
    unsigned ku = (key & 0x80000000u) ? (key ^ 0x80000000u) : ~key;
    const float gmax = fabsf(__uint_as_float(ku));
    const float sc_to = 5.0f / gmax;
    const float sc_from = gmax / 5.0f;

    // ---- z0 = sc_to * u, single f16, swizzled ----
    for (int i = tid; i < 64 * FC; i += 512) {
        int b = i / FC, fc = i - b * FC;
        float z = sc_to * u[(long)row0 * FC + i];
        int idx = b * FC + ((fc & ~31) | ((fc & 31) ^ ((b & 3) << 3)));
        zh[idx] = (f16)z;
    }

    floatx4 R[32];
#pragma unroll
    for (int i = 0; i < 32; i++) R[i] = (floatx4){0.f, 0.f, 0.f, 0.f};

    const f16* __restrict__ w1h = (const f16*)(ws + OFF_W1);
    const f16* __restrict__ w2h = (const f16*)(ws + OFF_W2);

    const int brow = (w & 3) * 16 + l15;   // phase-B A-operand row (b)
    const int fh = (w >> 2) * 3;           // first of 3 f-tiles for this wave
    const int aswz = (brow & 7) << 3;
    const long hrow = (long)brow * NRI;

    float gcur = 0.0f;                     // g for n-pair {w*128+2*lane, +1}

#pragma unroll 1
    for (int l = 0; l < LAYERS; l++) {
        __syncthreads();   // z_lds ready (z0 or previous epilogue); H free for overwrite

        // ---- phase A: R = g_{l-1}*R + z @ W1   (C^T = W1^T(A) x z^T(B)) ----
        if (l > 0) {
#pragma unroll
            for (int ntl = 0; ntl < 8; ntl++) {
                float ga = __shfl(gcur, ntl * 8 + q * 2, 64);
                float gb = __shfl(gcur, ntl * 8 + q * 2 + 1, 64);
#pragma unroll
                for (int bt = 0; bt < 4; bt++) {
                    R[ntl * 4 + bt][0] *= ga;
                    R[ntl * 4 + bt][1] *= ga;
                    R[ntl * 4 + bt][2] *= gb;
                    R[ntl * 4 + bt][3] *= gb;
                }
            }
        }
#pragma unroll
        for (int kc = 0; kc < 3; kc++) {
            half8 Bh[4];
#pragma unroll
            for (int bt = 0; bt < 4; bt++) {
                int b = bt * 16 + l15;
                int zi = b * FC + kc * 32 + ((q ^ (b & 3)) << 3);
                Bh[bt] = *(const half8*)(zh + zi);
            }
#pragma unroll
            for (int ntl = 0; ntl < 8; ntl++) {
                int wi = (((w * 8 + ntl) * 3 + kc) * 64 + lane) * 8;
                half8 Ah = *(const half8*)(w1h + wi);
#pragma unroll
                for (int bt = 0; bt < 4; bt++) {
                    R[ntl*4+bt] = __builtin_amdgcn_mfma_f32_16x16x32_f16(Ah, Bh[bt], R[ntl*4+bt], 0, 0, 0);
                }
            }
        }

        // ---- per-n partial sums of R^2 -> private block row (no contention) ----
        {
            float* part = ws + OFF_PART + (long)blockIdx.x * NRI;
#pragma unroll
            for (int ntl = 0; ntl < 8; ntl++) {
                floatx4 ps;
#pragma unroll
                for (int r = 0; r < 4; r++) {
                    float p = R[ntl*4+0][r] * R[ntl*4+0][r];
                    p = fmaf(R[ntl*4+1][r], R[ntl*4+1][r], p);
                    p = fmaf(R[ntl*4+2][r], R[ntl*4+2][r], p);
                    p = fmaf(R[ntl*4+3][r], R[ntl*4+3][r], p);
                    p += __shfl_xor(p, 1, 64);
                    p += __shfl_xor(p, 2, 64);
                    p += __shfl_xor(p, 4, 64);
                    p += __shfl_xor(p, 8, 64);
                    ps[r] = p;
                }
                if (l15 == 0) {
                    int n = w * 128 + ntl * 16 + q * 4;
                    coh_store8(part + n, ps[0], ps[1]);
                    coh_store8(part + n + 2, ps[2], ps[3]);
                }
            }
        }
        gbar2(ws, epoch); epoch++;

        // ---- combine: this block reduces n0..n0+3 over all 256 blocks (wave 0) ----
        if (w == 0) {
            const int n0 = blockIdx.x * 4;
            const float* pb = ws + OFF_PART;
            floatx4 cs = {0.f, 0.f, 0.f, 0.f};
#pragma unroll
            for (int s4 = 0; s4 < 4; s4++) {
                long off = (long)(s4 * 64 + lane) * NRI + n0;
                unsigned long long a = __hip_atomic_load((const unsigned long long*)(pb + off),
                                                         __ATOMIC_RELAXED, __HIP_MEMORY_SCOPE_AGENT);
                unsigned long long b = __hip_atomic_load((const unsigned long long*)(pb + off + 2),
                                                         __ATOMIC_RELAXED, __HIP_MEMORY_SCOPE_AGENT);
                cs[0] += __uint_as_float((unsigned)a);
                cs[1] += __uint_as_float((unsigned)(a >> 32));
                cs[2] += __uint_as_float((unsigned)b);
                cs[3] += __uint_as_float((unsigned)(b >> 32));
            }
#pragma unroll
            for (int sh = 1; sh < 64; sh <<= 1) {
                cs[0] += __shfl_xor(cs[0], sh, 64);
                cs[1] += __shfl_xor(cs[1], sh, 64);
                cs[2] += __shfl_xor(cs[2], sh, 64);
                cs[3] += __shfl_xor(cs[3], sh, 64);
            }
            if (lane == 0) {
                coh_store8(ws + OFF_FIN + n0, cs[0], cs[1]);
                coh_store8(ws + OFF_FIN + n0 + 2, cs[2], cs[3]);
            }
        }
        gbar2(ws, epoch); epoch++;

        // ---- readback + gate (wave-local; n-pair 2t,2t+1 shares one g) ----
        {
            int n = w * 128 + lane * 2;
            unsigned long long pv = __hip_atomic_load((const unsigned long long*)(ws + OFF_FIN + n),
                                                      __ATOMIC_RELAXED, __HIP_MEMORY_SCOPE_AGENT);
            float sa = __uint_as_float((unsigned)pv);
            float sb = __uint_as_float((unsigned)(pv >> 32));
            float rm = sqrtf((sa + sb) * (1.0f / 16384.0f));
            gcur = 1.0f / (1.0f + expf(-s1 * (rm - s2)));
        }

        // ---- phase B: stage H = g*R once (single f16, swizzled), one barrier ----
#pragma unroll
        for (int ntl = 0; ntl < 8; ntl++) {
            float ga = __shfl(gcur, ntl * 8 + q * 2, 64);
            float gb = __shfl(gcur, ntl * 8 + q * 2 + 1, 64);
            floatx4 g4 = {ga, ga, gb, gb};
            int col = w * 128 + ntl * 16 + q * 4;
#pragma unroll
            for (int bt = 0; bt < 4; bt++) {
                int row = bt * 16 + l15;
                half4 vh;
#pragma unroll
                for (int r = 0; r < 4; r++) vh[r] = (f16)(g4[r] * R[ntl * 4 + bt][r]);
                *(half4*)(Hs + row * NRI + (col ^ ((row & 7) << 3))) = vh;
            }
        }
        __syncthreads();

        // ---- barrier-free K loop: h = H @ W2 (A = H f16, B = W2 single f16) ----
        floatx4 acc[3];
#pragma unroll
        for (int i = 0; i < 3; i++) acc[i] = (floatx4){0.f, 0.f, 0.f, 0.f};
#pragma unroll 4
        for (int kg = 0; kg < 32; kg++) {
            half8 Ah = *(const half8*)(Hs + hrow + ((kg * 32 + q * 8) ^ aswz));
#pragma unroll
            for (int ft = 0; ft < 3; ft++) {
                int wi = (((fh + ft) * 32 + kg) * 64 + lane) * 8;
                half8 Wh = *(const half8*)(w2h + wi);
                acc[ft] = __builtin_amdgcn_mfma_f32_16x16x32_f16(Ah, Wh, acc[ft], 0, 0, 0);
            }
        }

        // ---- epilogue: z = u*sc_to - h  (or final out = h*sc_from) ----
        if (l < LAYERS - 1) {
#pragma unroll
            for (int ft = 0; ft < 3; ft++) {
                int fcg = (fh + ft) * 16 + l15;
#pragma unroll
                for (int r = 0; r < 4; r++) {
                    int b = (w & 3) * 16 + q * 4 + r;
                    float z = fmaf(sc_to, u[(long)(row0 + b) * FC + fcg], -acc[ft][r]);
                    int idx = b * FC + ((fcg & ~31) | ((fcg & 31) ^ ((b & 3) << 3)));
                    zh[idx] = (f16)z;
                }
            }
        } else {
#pragma unroll
            for (int ft = 0; ft < 3; ft++) {
                int fcg = (fh + ft) * 16 + l15;
#pragma unroll
                for (int r = 0; r < 4; r++) {
                    int b = (w & 3) * 16 + q * 4 + r;
                    out[(long)(row0 + b) * FC + fcg] = acc[ft][r] * sc_from;
                }
            }
        }
    }
}

extern "C" void kernel_launch(void* const* d_in, const int* in_sizes, int n_in,
                              void* d_out, int out_size, void* d_ws, size_t ws_size,
                              hipStream_t stream) {
    (void)in_sizes; (void)n_in; (void)out_size; (void)ws_size;
    const float* u  = (const float*)d_in[0];
    const float* S1 = (const float*)d_in[1];
    const float* S2 = (const float*)d_in[2];
    float* out = (float*)d_out;
    float* ws  = (float*)d_ws;

    static int inited = 0;
    if (!inited) {
        hipFuncSetAttribute((const void*)kmain, hipFuncAttributeMaxDynamicSharedMemorySize, SMEM_BYTES);
        inited = 1;
    }

    ksetup<<<1, 256, 0, stream>>>(ws);
    kwf<<<768, 256, 0, stream>>>(ws);

    void* args[] = {(void*)&u, (void*)&S1, (void*)&S2, (void*)&out, (void*)&ws};
    hipLaunchCooperativeKernel((const void*)kmain, dim3(NBLK), dim3(512), args,
                               (unsigned)SMEM_BYTES, stream);
}